// Round 8
// baseline (137.050 us; speedup 1.0000x reference)
//
#include <hip/hip_runtime.h>
#include <hip/hip_bf16.h>
#include <math.h>

#define BS 4096
#define DIM 2048
#define EPSV 1e-6f

typedef unsigned short u16;
typedef float f32x4 __attribute__((ext_vector_type(4)));
typedef unsigned int u32x4 __attribute__((ext_vector_type(4)));
typedef __bf16 bf16x8 __attribute__((ext_vector_type(8)));

__device__ inline u16 f2bf(float f) {
  unsigned u = __float_as_uint(f);
  unsigned r = (u + 0x7fffu + ((u >> 16) & 1u)) >> 16;
  return (u16)r;
}

__device__ inline void gload16(const u16* g, u16* l) {
  __builtin_amdgcn_global_load_lds((const __attribute__((address_space(1))) unsigned int*)g,
                                   (__attribute__((address_space(3))) unsigned int*)l,
                                   16, 0, 0);
}

// ---------------- prep: f32 -> bf16 copies + per-row sum / sumsq ----------------
__global__ __launch_bounds__(256) void prep_kernel(
    const float* __restrict__ h1, const float* __restrict__ h2,
    u16* __restrict__ A, u16* __restrict__ B,
    float* __restrict__ sq1, float* __restrict__ s1,
    float* __restrict__ sq2, float* __restrict__ s2) {
  int b = blockIdx.x;
  const float* src; u16* dst; float* sqo; float* so; int row;
  if (b < BS) { src = h1; dst = A; sqo = sq1; so = s1; row = b; }
  else        { src = h2; dst = B; sqo = sq2; so = s2; row = b - BS; }
  src += (size_t)row * DIM;
  dst += (size_t)row * DIM;
  int t = threadIdx.x;
  float sq = 0.f, s = 0.f;
#pragma unroll
  for (int it = 0; it < DIM / (256 * 4); ++it) {
    int idx = (it * 256 + t) * 4;
    float4 v = *(const float4*)(src + idx);
    sq += v.x * v.x + v.y * v.y + v.z * v.z + v.w * v.w;
    s  += v.x + v.y + v.z + v.w;
    ushort4 o;
    o.x = f2bf(v.x); o.y = f2bf(v.y); o.z = f2bf(v.z); o.w = f2bf(v.w);
    *(ushort4*)(dst + idx) = o;
  }
#pragma unroll
  for (int m = 32; m; m >>= 1) { sq += __shfl_xor(sq, m, 64); s += __shfl_xor(s, m, 64); }
  __shared__ float lsq[4], ls[4];
  if ((t & 63) == 0) { lsq[t >> 6] = sq; ls[t >> 6] = s; }
  __syncthreads();
  if (t == 0) {
    sqo[row] = lsq[0] + lsq[1] + lsq[2] + lsq[3];
    so[row]  = ls[0] + ls[1] + ls[2] + ls[3];
  }
}

// ---------------- GEMM: 256x256 tile, BK=32, 4-buffer rotation, m201 8-phase rhythm ----------------
// 512 threads = 8 waves (2M x 4N), per-wave output 128x64. LDS 128 KiB, 1 block/CU.
// Per K32-tile: 2 phases x {ds_reads, 2 gloads, barrier, lgkmcnt(0)+sched_barrier,
// setprio(1)+16 MFMA+setprio(0), barrier}. B-frags register-reused across both phases.
// Counted vmcnt(8) steady-state (T4); zero-conflict swizzle chunk^=(row>>1)&3 (T2).
#define BK 32
#define NT (DIM / BK)

__global__ __launch_bounds__(512, 2) void gemm_select_kernel(
    const u16* __restrict__ A, const u16* __restrict__ B,
    const float* __restrict__ sq1, const float* __restrict__ s1,
    const float* __restrict__ sq2, const float* __restrict__ s2,
    const int* __restrict__ lab1, const int* __restrict__ lab2,
    float4* __restrict__ part) {
  __shared__ __align__(16) u16 lds[4][2][8192];
  int tid = threadIdx.x;
  int w = tid >> 6, l = tid & 63;
  int wr = w >> 2, wc = w & 3;
  int g = l >> 4, c = l & 15;
  int by = blockIdx.x >> 4, bx = blockIdx.x & 15;
  const int rowB = by * 256, colB = bx * 256;

  // --- staging (pre-swizzled global source, linear LDS dest; rule #21) ---
  // physical byte P = q*8192 + w*1024 + l*16 -> row = q*128 + w*16 + (l>>2),
  // phys chunk = l&3; logical chunk = (l&3) ^ ((row>>1)&3) = (l&3) ^ ((l>>3)&3)
  int srow = w * 16 + (l >> 2);
  int schunk = (l & 3) ^ ((l >> 3) & 3);
  const u16* gA0 = A + (size_t)(rowB + srow) * DIM + schunk * 8;
  const u16* gA1 = A + (size_t)(rowB + 128 + srow) * DIM + schunk * 8;
  const u16* gB0 = B + (size_t)(colB + srow) * DIM + schunk * 8;
  const u16* gB1 = B + (size_t)(colB + 128 + srow) * DIM + schunk * 8;

#define STAGE_A(T) do { int b_ = (T) & 3; size_t k_ = (size_t)(T) * BK;          \
    gload16(gA0 + k_, &lds[b_][0][0 * 4096 + w * 512]);                          \
    gload16(gA1 + k_, &lds[b_][0][1 * 4096 + w * 512]); } while (0)
#define STAGE_B(T) do { int b_ = (T) & 3; size_t k_ = (size_t)(T) * BK;          \
    gload16(gB0 + k_, &lds[b_][1][0 * 4096 + w * 512]);                          \
    gload16(gB1 + k_, &lds[b_][1][1 * 4096 + w * 512]); } while (0)

  // --- fragment read offsets: byte = row*64 + ((g ^ ((row>>1)&3))<<4), (row>>1)&3 == (c>>1)&3 ---
  unsigned ldsBase = (unsigned)(size_t)(__attribute__((address_space(3))) u16*)&lds[0][0][0];
  unsigned xo = (unsigned)((g ^ ((c >> 1) & 3)) << 4);
  unsigned offA[8], offB[4];
#pragma unroll
  for (int mi = 0; mi < 8; ++mi) offA[mi] = (unsigned)((wr * 128 + mi * 16 + c) * 64) + xo;
#pragma unroll
  for (int ni = 0; ni < 4; ++ni) offB[ni] = 16384u + (unsigned)((wc * 64 + ni * 16 + c) * 64) + xo;

  f32x4 acc[8][4] = {};

  // --- prologue: stage tiles 0,1,2; wait tile 0 landed (12 outstanding -> 8) ---
  STAGE_A(0); STAGE_B(0); STAGE_A(1); STAGE_B(1); STAGE_A(2); STAGE_B(2);
  asm volatile("s_waitcnt vmcnt(8)" ::: "memory");
  asm volatile("s_barrier" ::: "memory");

  for (int kt = 0; kt < NT; ++kt) {
    unsigned bb = ldsBase + (unsigned)((kt & 3) << 15);
    u32x4 rb[4], ra0[4], ra1[4];
    // ---- phase A: read B(0-3) + A(0-3); stage A-half of kt+3 ----
#pragma unroll
    for (int ni = 0; ni < 4; ++ni)
      asm volatile("ds_read_b128 %0, %1" : "=v"(rb[ni]) : "v"(bb + offB[ni]));
#pragma unroll
    for (int mi = 0; mi < 4; ++mi)
      asm volatile("ds_read_b128 %0, %1" : "=v"(ra0[mi]) : "v"(bb + offA[mi]));
    if (kt + 3 < NT) STAGE_A(kt + 3);
    asm volatile("s_barrier" ::: "memory");
    asm volatile("s_waitcnt lgkmcnt(0)" ::: "memory");
    __builtin_amdgcn_sched_barrier(0);
    __builtin_amdgcn_s_setprio(1);
#pragma unroll
    for (int mi = 0; mi < 4; ++mi) {
      bf16x8 a = __builtin_bit_cast(bf16x8, ra0[mi]);
#pragma unroll
      for (int ni = 0; ni < 4; ++ni)
        acc[mi][ni] = __builtin_amdgcn_mfma_f32_16x16x32_bf16(
            a, __builtin_bit_cast(bf16x8, rb[ni]), acc[mi][ni], 0, 0, 0);
    }
    __builtin_amdgcn_s_setprio(0);
    asm volatile("s_barrier" ::: "memory");
    // ---- phase B: read A(4-7); stage B-half of kt+3 ----
#pragma unroll
    for (int mi = 0; mi < 4; ++mi)
      asm volatile("ds_read_b128 %0, %1" : "=v"(ra1[mi]) : "v"(bb + offA[4 + mi]));
    if (kt + 3 < NT) STAGE_B(kt + 3);
    asm volatile("s_barrier" ::: "memory");
    asm volatile("s_waitcnt lgkmcnt(0)" ::: "memory");
    __builtin_amdgcn_sched_barrier(0);
    __builtin_amdgcn_s_setprio(1);
#pragma unroll
    for (int mi = 0; mi < 4; ++mi) {
      bf16x8 a = __builtin_bit_cast(bf16x8, ra1[mi]);
#pragma unroll
      for (int ni = 0; ni < 4; ++ni)
        acc[4 + mi][ni] = __builtin_amdgcn_mfma_f32_16x16x32_bf16(
            a, __builtin_bit_cast(bf16x8, rb[ni]), acc[4 + mi][ni], 0, 0, 0);
    }
    __builtin_amdgcn_s_setprio(0);
    // counted waits: guarantee tile kt+1 landed; never drain to 0 mid-loop
    if (kt < NT - 3)       asm volatile("s_waitcnt vmcnt(8)" ::: "memory");
    else if (kt == NT - 3) asm volatile("s_waitcnt vmcnt(4)" ::: "memory");
    else if (kt == NT - 2) asm volatile("s_waitcnt vmcnt(0)" ::: "memory");
    asm volatile("s_barrier" ::: "memory");
  }
#undef STAGE_A
#undef STAGE_B

  // --- epilogue: dist + fused hard-pos/neg partial select (verified) ---
  float pc_[4]; int l2v[4]; int jcol[4];
#pragma unroll
  for (int ni = 0; ni < 4; ++ni) {
    int j = colB + wc * 64 + ni * 16 + c;
    jcol[ni] = j;
    l2v[ni] = lab2[j];
    pc_[ni] = sq2[j] - 2.0f * EPSV * s2[j];
  }
  const float cst = (float)DIM * EPSV * EPSV;
  int partCol = bx * 4 + wc;

#pragma unroll
  for (int mi = 0; mi < 8; ++mi) {
    float posV[4], negV[4]; int posI[4], negI[4];
    float pr[4]; int l1v[4];
#pragma unroll
    for (int r = 0; r < 4; ++r) {
      int i = rowB + wr * 128 + mi * 16 + g * 4 + r;
      l1v[r] = lab1[i];
      pr[r] = sq1[i] + 2.0f * EPSV * s1[i] + cst;
      posV[r] = -3.0e38f; posI[r] = 0x7fffffff;
      negV[r] =  3.0e38f; negI[r] = 0x7fffffff;
    }
#pragma unroll
    for (int ni = 0; ni < 4; ++ni) {
#pragma unroll
      for (int r = 0; r < 4; ++r) {
        float dot = acc[mi][ni][r];
        float d2 = pr[r] + pc_[ni] - 2.0f * dot;
        float dist = sqrtf(fmaxf(d2, 0.0f));
        bool same = (l1v[r] == l2v[ni]);
        float pv = same ? dist : -3.0e38f;
        float nv = same ?  3.0e38f : dist;
        if (pv > posV[r] || (pv == posV[r] && jcol[ni] < posI[r])) { posV[r] = pv; posI[r] = jcol[ni]; }
        if (nv < negV[r] || (nv == negV[r] && jcol[ni] < negI[r])) { negV[r] = nv; negI[r] = jcol[ni]; }
      }
    }
#pragma unroll
    for (int m = 1; m < 16; m <<= 1) {
#pragma unroll
      for (int r = 0; r < 4; ++r) {
        float ov = __shfl_xor(posV[r], m, 64);
        int   oi = __shfl_xor(posI[r], m, 64);
        if (ov > posV[r] || (ov == posV[r] && oi < posI[r])) { posV[r] = ov; posI[r] = oi; }
        float nv2 = __shfl_xor(negV[r], m, 64);
        int   on  = __shfl_xor(negI[r], m, 64);
        if (nv2 < negV[r] || (nv2 == negV[r] && on < negI[r])) { negV[r] = nv2; negI[r] = on; }
      }
    }
    if (c == 0) {
#pragma unroll
      for (int r = 0; r < 4; ++r) {
        int i = rowB + wr * 128 + mi * 16 + g * 4 + r;
        float4 o;
        o.x = posV[r]; o.y = __int_as_float(posI[r]);
        o.z = negV[r]; o.w = __int_as_float(negI[r]);
        part[(size_t)i * 64 + partCol] = o;
      }
    }
  }
}

// ---------------- combine 64 column-chunk partials per row ----------------
__global__ __launch_bounds__(256) void reduce_kernel(const float4* __restrict__ part,
                                                     int4* __restrict__ sel) {
  int row = blockIdx.x * 4 + (threadIdx.x >> 6);
  int lane = threadIdx.x & 63;
  float4 p = part[(size_t)row * 64 + lane];
  float posV = p.x; int posI = __float_as_int(p.y);
  float negV = p.z; int negI = __float_as_int(p.w);
#pragma unroll
  for (int m = 1; m < 64; m <<= 1) {
    float ov = __shfl_xor(posV, m, 64);
    int   oi = __shfl_xor(posI, m, 64);
    if (ov > posV || (ov == posV && oi < posI)) { posV = ov; posI = oi; }
    float nv = __shfl_xor(negV, m, 64);
    int   on = __shfl_xor(negI, m, 64);
    if (nv < negV || (nv == negV && on < negI)) { negV = nv; negI = on; }
  }
  if (lane == 0) {
    int valid = (posV > -1.0e38f && negV < 1.0e38f) ? 1 : 0;
    sel[row] = make_int4(posI, negI, valid, 0);
  }
}

// ---------------- recompute d_ap / d_an exactly (f32, direct formula) ----------------
__global__ __launch_bounds__(256) void loss_kernel(
    const float* __restrict__ h1, const float* __restrict__ h2,
    const int4* __restrict__ sel, float* __restrict__ perrow, float* __restrict__ validf) {
  int row = blockIdx.x;
  int t = threadIdx.x;
  int4 sl = sel[row];
  if (!sl.z) { if (t == 0) { perrow[row] = 0.f; validf[row] = 0.f; } return; }
  const float* x = h1 + (size_t)row * DIM;
  const float* p = h2 + (size_t)sl.x * DIM;
  const float* n = h2 + (size_t)sl.y * DIM;
  float sap = 0.f, san = 0.f;
#pragma unroll
  for (int it = 0; it < DIM / (256 * 4); ++it) {
    int idx = (it * 256 + t) * 4;
    float4 xv = *(const float4*)(x + idx);
    float4 pv = *(const float4*)(p + idx);
    float4 nv = *(const float4*)(n + idx);
    float d;
    d = xv.x - pv.x + EPSV; sap += d * d;
    d = xv.y - pv.y + EPSV; sap += d * d;
    d = xv.z - pv.z + EPSV; sap += d * d;
    d = xv.w - pv.w + EPSV; sap += d * d;
    d = xv.x - nv.x + EPSV; san += d * d;
    d = xv.y - nv.y + EPSV; san += d * d;
    d = xv.z - nv.z + EPSV; san += d * d;
    d = xv.w - nv.w + EPSV; san += d * d;
  }
#pragma unroll
  for (int m = 32; m; m >>= 1) { sap += __shfl_xor(sap, m, 64); san += __shfl_xor(san, m, 64); }
  __shared__ float lsap[4], lsan[4];
  if ((t & 63) == 0) { lsap[t >> 6] = sap; lsan[t >> 6] = san; }
  __syncthreads();
  if (t == 0) {
    sap = lsap[0] + lsap[1] + lsap[2] + lsap[3];
    san = lsan[0] + lsan[1] + lsan[2] + lsan[3];
    perrow[row] = fmaxf(sqrtf(sap) - sqrtf(san), 0.0f);
    validf[row] = 1.0f;
  }
}

// ---------------- deterministic finalize (fixed-order tree) ----------------
__global__ __launch_bounds__(256) void finalize_kernel(const float* __restrict__ perrow,
                                                       const float* __restrict__ validf,
                                                       float* __restrict__ out) {
  int t = threadIdx.x;
  float s = 0.f, cv = 0.f;
  for (int i = t; i < BS; i += 256) { s += perrow[i]; cv += validf[i]; }
  __shared__ float ls[256], lc[256];
  ls[t] = s; lc[t] = cv;
  __syncthreads();
  for (int m = 128; m; m >>= 1) {
    if (t < m) { ls[t] += ls[t + m]; lc[t] += lc[t + m]; }
    __syncthreads();
  }
  if (t == 0) out[0] = (lc[0] > 0.f) ? ls[0] / fmaxf(lc[0], 1.f) : 0.f;
}

extern "C" void kernel_launch(void* const* d_in, const int* in_sizes, int n_in,
                              void* d_out, int out_size, void* d_ws, size_t ws_size,
                              hipStream_t stream) {
  const float* h1 = (const float*)d_in[0];
  const float* h2 = (const float*)d_in[1];
  const int* lab1 = (const int*)d_in[2];
  const int* lab2 = (const int*)d_in[3];

  char* ws = (char*)d_ws;
  u16* A = (u16*)ws;
  u16* B = (u16*)(ws + (size_t)BS * DIM * 2);
  size_t off = (size_t)BS * DIM * 4;
  float* sq1 = (float*)(ws + off); off += BS * 4;
  float* s1  = (float*)(ws + off); off += BS * 4;
  float* sq2 = (float*)(ws + off); off += BS * 4;
  float* s2  = (float*)(ws + off); off += BS * 4;
  float4* part = (float4*)(ws + off); off += (size_t)BS * 64 * 16;
  int4* sel = (int4*)(ws + off); off += BS * 16;
  float* perrow = (float*)(ws + off); off += BS * 4;
  float* validf = (float*)(ws + off); off += BS * 4;

  prep_kernel<<<2 * BS, 256, 0, stream>>>(h1, h2, A, B, sq1, s1, sq2, s2);
  gemm_select_kernel<<<256, 512, 0, stream>>>(A, B, sq1, s1, sq2, s2, lab1, lab2, part);
  reduce_kernel<<<BS / 4, 256, 0, stream>>>(part, sel);
  loss_kernel<<<BS, 256, 0, stream>>>(h1, h2, sel, perrow, validf);
  finalize_kernel<<<1, 256, 0, stream>>>(perrow, validf, (float*)d_out);
}

// Round 10
// 116.378 us; speedup vs baseline: 1.1776x; 1.1776x over previous
//
#include <hip/hip_runtime.h>
#include <hip/hip_bf16.h>
#include <math.h>

#define BS 4096
#define DIM 2048
#define EPSV 1e-6f

typedef unsigned short u16;
typedef float f32x4 __attribute__((ext_vector_type(4)));
typedef __bf16 bf16x8 __attribute__((ext_vector_type(8)));

__device__ inline u16 f2bf(float f) {
  unsigned u = __float_as_uint(f);
  unsigned r = (u + 0x7fffu + ((u >> 16) & 1u)) >> 16;
  return (u16)r;
}

__device__ inline void gload16(const u16* g, u16* l) {
  __builtin_amdgcn_global_load_lds((const __attribute__((address_space(1))) unsigned int*)g,
                                   (__attribute__((address_space(3))) unsigned int*)l,
                                   16, 0, 0);
}

// ---------------- prep: f32 -> bf16 copies + per-row sum / sumsq ----------------
__global__ __launch_bounds__(256) void prep_kernel(
    const float* __restrict__ h1, const float* __restrict__ h2,
    u16* __restrict__ A, u16* __restrict__ B,
    float* __restrict__ sq1, float* __restrict__ s1,
    float* __restrict__ sq2, float* __restrict__ s2) {
  int b = blockIdx.x;
  const float* src; u16* dst; float* sqo; float* so; int row;
  if (b < BS) { src = h1; dst = A; sqo = sq1; so = s1; row = b; }
  else        { src = h2; dst = B; sqo = sq2; so = s2; row = b - BS; }
  src += (size_t)row * DIM;
  dst += (size_t)row * DIM;
  int t = threadIdx.x;
  float sq = 0.f, s = 0.f;
#pragma unroll
  for (int it = 0; it < DIM / (256 * 4); ++it) {
    int idx = (it * 256 + t) * 4;
    float4 v = *(const float4*)(src + idx);
    sq += v.x * v.x + v.y * v.y + v.z * v.z + v.w * v.w;
    s  += v.x + v.y + v.z + v.w;
    ushort4 o;
    o.x = f2bf(v.x); o.y = f2bf(v.y); o.z = f2bf(v.z); o.w = f2bf(v.w);
    *(ushort4*)(dst + idx) = o;
  }
#pragma unroll
  for (int m = 32; m; m >>= 1) { sq += __shfl_xor(sq, m, 64); s += __shfl_xor(s, m, 64); }
  __shared__ float lsq[4], ls[4];
  if ((t & 63) == 0) { lsq[t >> 6] = sq; ls[t >> 6] = s; }
  __syncthreads();
  if (t == 0) {
    sqo[row] = lsq[0] + lsq[1] + lsq[2] + lsq[3];
    so[row]  = ls[0] + ls[1] + ls[2] + ls[3];
  }
}

// ---------------- GEMM: 256x128 tile, BK=32, double-buffer, 2 blocks/CU ----------------
// 512 threads = 8 waves (4M x 2N), per-wave output 64x64 -> acc[4][4] = 64 regs,
// total <=128/wave (__launch_bounds__(512,4)) => 2 blocks/CU, 4 waves/SIMD.
// Cross-block TLP hides LDS/drain stalls (m97/m114 mechanism). One __syncthreads
// per K-tile; compiler schedules ds_read/lgkmcnt fine-grained. Zero-conflict
// swizzle: chunk ^= (row>>1)&3 (both sides).
#define BK 32
#define NT (DIM / BK)

__global__ __launch_bounds__(512, 4) void gemm_select_kernel(
    const u16* __restrict__ A, const u16* __restrict__ B,
    const float* __restrict__ sq1, const float* __restrict__ s1,
    const float* __restrict__ sq2, const float* __restrict__ s2,
    const int* __restrict__ lab1, const int* __restrict__ lab2,
    float4* __restrict__ part) {
  __shared__ __align__(16) u16 lds[2][12288];  // per buffer: A 256x32 (8192) + B 128x32 (4096)
  int tid = threadIdx.x;
  int w = tid >> 6, l = tid & 63;
  int wr = w >> 1, wc = w & 1;
  int g = l >> 4, c = l & 15;
  int by = blockIdx.x >> 5, bx = blockIdx.x & 31;
  const int rowB = by * 256, colB = bx * 128;

  // staging: pre-swizzled global source, linear LDS dest (rule #21)
  // dest 16B-unit idx = q*512 + tid -> row = q*128 + (tid>>2), phys chunk = tid&3
  // logical chunk = (tid&3) ^ ((row>>1)&3) = (tid&3) ^ ((tid>>3)&3)
  int srow = tid >> 2;
  int schunk = (tid & 3) ^ ((tid >> 3) & 3);
  const u16* gA0 = A + (size_t)(rowB + srow) * DIM + schunk * 8;
  const u16* gA1 = A + (size_t)(rowB + 128 + srow) * DIM + schunk * 8;
  const u16* gB0 = B + (size_t)(colB + srow) * DIM + schunk * 8;

#define STAGE(T) do { int b_ = (T) & 1; size_t k_ = (size_t)(T) * BK;            \
    gload16(gA0 + k_, &lds[b_][0]    + tid * 8);                                 \
    gload16(gA1 + k_, &lds[b_][4096] + tid * 8);                                 \
    gload16(gB0 + k_, &lds[b_][8192] + tid * 8); } while (0)

  // fragment reads (swizzled): u16 idx = row*32 + ((g ^ ((c>>1)&3))*8)
  const int xc = (g ^ ((c >> 1) & 3)) * 8;

  f32x4 acc[4][4] = {};

  STAGE(0);
  __syncthreads();

  for (int kt = 0; kt < NT; ++kt) {
    const u16* buf = lds[kt & 1];
    if (kt + 1 < NT) STAGE(kt + 1);
    bf16x8 af[4], bfr[4];
#pragma unroll
    for (int mi = 0; mi < 4; ++mi)
      af[mi] = *(const bf16x8*)&buf[(wr * 64 + mi * 16 + c) * 32 + xc];
#pragma unroll
    for (int ni = 0; ni < 4; ++ni)
      bfr[ni] = *(const bf16x8*)&buf[8192 + (wc * 64 + ni * 16 + c) * 32 + xc];
#pragma unroll
    for (int mi = 0; mi < 4; ++mi)
#pragma unroll
      for (int ni = 0; ni < 4; ++ni)
        acc[mi][ni] = __builtin_amdgcn_mfma_f32_16x16x32_bf16(af[mi], bfr[ni], acc[mi][ni], 0, 0, 0);
    __syncthreads();
  }
#undef STAGE

  // --- epilogue: dist + fused hard-pos/neg partial select ---
  float pc_[4]; int l2v[4]; int jcol[4];
#pragma unroll
  for (int ni = 0; ni < 4; ++ni) {
    int j = colB + wc * 64 + ni * 16 + c;
    jcol[ni] = j;
    l2v[ni] = lab2[j];
    pc_[ni] = sq2[j] - 2.0f * EPSV * s2[j];
  }
  const float cst = (float)DIM * EPSV * EPSV;
  int partCol = bx * 2 + wc;

#pragma unroll
  for (int mi = 0; mi < 4; ++mi) {
    float posV[4], negV[4]; int posI[4], negI[4];
    float pr[4]; int l1v[4];
#pragma unroll
    for (int r = 0; r < 4; ++r) {
      int i = rowB + wr * 64 + mi * 16 + g * 4 + r;
      l1v[r] = lab1[i];
      pr[r] = sq1[i] + 2.0f * EPSV * s1[i] + cst;
      posV[r] = -3.0e38f; posI[r] = 0x7fffffff;
      negV[r] =  3.0e38f; negI[r] = 0x7fffffff;
    }
#pragma unroll
    for (int ni = 0; ni < 4; ++ni) {
#pragma unroll
      for (int r = 0; r < 4; ++r) {
        float dot = acc[mi][ni][r];
        float d2 = pr[r] + pc_[ni] - 2.0f * dot;
        float dist = sqrtf(fmaxf(d2, 0.0f));
        bool same = (l1v[r] == l2v[ni]);
        float pv = same ? dist : -3.0e38f;
        float nv = same ?  3.0e38f : dist;
        if (pv > posV[r] || (pv == posV[r] && jcol[ni] < posI[r])) { posV[r] = pv; posI[r] = jcol[ni]; }
        if (nv < negV[r] || (nv == negV[r] && jcol[ni] < negI[r])) { negV[r] = nv; negI[r] = jcol[ni]; }
      }
    }
#pragma unroll
    for (int m = 1; m < 16; m <<= 1) {
#pragma unroll
      for (int r = 0; r < 4; ++r) {
        float ov = __shfl_xor(posV[r], m, 64);
        int   oi = __shfl_xor(posI[r], m, 64);
        if (ov > posV[r] || (ov == posV[r] && oi < posI[r])) { posV[r] = ov; posI[r] = oi; }
        float nv2 = __shfl_xor(negV[r], m, 64);
        int   on  = __shfl_xor(negI[r], m, 64);
        if (nv2 < negV[r] || (nv2 == negV[r] && on < negI[r])) { negV[r] = nv2; negI[r] = on; }
      }
    }
    if (c == 0) {
#pragma unroll
      for (int r = 0; r < 4; ++r) {
        int i = rowB + wr * 64 + mi * 16 + g * 4 + r;
        float4 o;
        o.x = posV[r]; o.y = __int_as_float(posI[r]);
        o.z = negV[r]; o.w = __int_as_float(negI[r]);
        part[(size_t)i * 64 + partCol] = o;
      }
    }
  }
}

// ---------------- combine 64 partials per row -> per-row loss directly ----------------
// posV/negV ARE d_ap/d_an (same expanded ||x-y+eps|| formula as reference).
__global__ __launch_bounds__(256) void reduce_kernel(const float4* __restrict__ part,
                                                     float* __restrict__ perrow,
                                                     float* __restrict__ validf) {
  int row = blockIdx.x * 4 + (threadIdx.x >> 6);
  int lane = threadIdx.x & 63;
  float4 p = part[(size_t)row * 64 + lane];
  float posV = p.x; int posI = __float_as_int(p.y);
  float negV = p.z; int negI = __float_as_int(p.w);
#pragma unroll
  for (int m = 1; m < 64; m <<= 1) {
    float ov = __shfl_xor(posV, m, 64);
    int   oi = __shfl_xor(posI, m, 64);
    if (ov > posV || (ov == posV && oi < posI)) { posV = ov; posI = oi; }
    float nv = __shfl_xor(negV, m, 64);
    int   on = __shfl_xor(negI, m, 64);
    if (nv < negV || (nv == negV && on < negI)) { negV = nv; negI = on; }
  }
  if (lane == 0) {
    bool valid = (posV > -1.0e38f && negV < 1.0e38f);
    perrow[row] = valid ? fmaxf(posV - negV, 0.0f) : 0.0f;
    validf[row] = valid ? 1.0f : 0.0f;
  }
}

// ---------------- deterministic finalize (fixed-order tree) ----------------
__global__ __launch_bounds__(256) void finalize_kernel(const float* __restrict__ perrow,
                                                       const float* __restrict__ validf,
                                                       float* __restrict__ out) {
  int t = threadIdx.x;
  float s = 0.f, cv = 0.f;
  for (int i = t; i < BS; i += 256) { s += perrow[i]; cv += validf[i]; }
  __shared__ float ls[256], lc[256];
  ls[t] = s; lc[t] = cv;
  __syncthreads();
  for (int m = 128; m; m >>= 1) {
    if (t < m) { ls[t] += ls[t + m]; lc[t] += lc[t + m]; }
    __syncthreads();
  }
  if (t == 0) out[0] = (lc[0] > 0.f) ? ls[0] / fmaxf(lc[0], 1.f) : 0.f;
}

extern "C" void kernel_launch(void* const* d_in, const int* in_sizes, int n_in,
                              void* d_out, int out_size, void* d_ws, size_t ws_size,
                              hipStream_t stream) {
  const float* h1 = (const float*)d_in[0];
  const float* h2 = (const float*)d_in[1];
  const int* lab1 = (const int*)d_in[2];
  const int* lab2 = (const int*)d_in[3];

  char* ws = (char*)d_ws;
  u16* A = (u16*)ws;
  u16* B = (u16*)(ws + (size_t)BS * DIM * 2);
  size_t off = (size_t)BS * DIM * 4;
  float* sq1 = (float*)(ws + off); off += BS * 4;
  float* s1  = (float*)(ws + off); off += BS * 4;
  float* sq2 = (float*)(ws + off); off += BS * 4;
  float* s2  = (float*)(ws + off); off += BS * 4;
  float4* part = (float4*)(ws + off); off += (size_t)BS * 64 * 16;
  float* perrow = (float*)(ws + off); off += BS * 4;
  float* validf = (float*)(ws + off); off += BS * 4;

  prep_kernel<<<2 * BS, 256, 0, stream>>>(h1, h2, A, B, sq1, s1, sq2, s2);
  gemm_select_kernel<<<512, 512, 0, stream>>>(A, B, sq1, s1, sq2, s2, lab1, lab2, part);
  reduce_kernel<<<BS / 4, 256, 0, stream>>>(part, perrow, validf);
  finalize_kernel<<<1, 256, 0, stream>>>(perrow, validf, (float*)d_out);
}